// Round 4
// baseline (435.817 us; speedup 1.0000x reference)
//
#include <hip/hip_runtime.h>
#include <math.h>

#define N_ROWS 8192
#define IN_F   512
#define RFF    2048
#define OUT_F  1000
#define OUT_PAD 1024
#define INV_RFF_SCALAR 0.03125f
#define MEAN_FIELD 25.0f

typedef __attribute__((ext_vector_type(8))) short short8;
typedef __attribute__((ext_vector_type(4))) float f32x4;

// ---------- bf16 helpers (RTN-even) ----------
__device__ __forceinline__ unsigned short f32_to_bf16(float f) {
    unsigned u = __float_as_uint(f);
    unsigned r = 0x7FFFu + ((u >> 16) & 1u);
    return (unsigned short)((u + r) >> 16);
}
__device__ __forceinline__ float bf16_to_f32(unsigned short h) {
    return __uint_as_float(((unsigned)h) << 16);
}

// fragment-chunk global source address for operand X (bf16, row-major, ld=ldx)
// chunk q (0..511): rt=q>>6 (16-row group), L=q&63 (lane): row r0+rt*16+(L&15),
// k = k0 + (L>>4)*8, 8 bf16 = 16B
__device__ __forceinline__ const uint4* gsrc(const unsigned short* X, int ldx,
                                             int r0, int k0, int q) {
    int rt = q >> 6, L = q & 63;
    int r = r0 + rt * 16 + (L & 15);
    int k = k0 + ((L >> 4) << 3);
    return (const uint4*)(X + (size_t)r * ldx + k);
}

// async global->LDS staging of one 128x32 bf16 tile (512 x 16B chunks).
// Wave w issues 2 instructions; chunk qb+lane lands at lds + (qb+lane)*16B.
__device__ __forceinline__ void stage_tile(const unsigned short* __restrict__ X, int ldx,
                                           int r0, int k0, unsigned short* lds,
                                           int w, int lane) {
    #pragma unroll
    for (int half = 0; half < 2; ++half) {
        int qb = half * 256 + w * 64;
        const uint4* g = gsrc(X, ldx, r0, k0, qb + lane);
        __builtin_amdgcn_global_load_lds(
            (const __attribute__((address_space(1))) void*)g,
            (__attribute__((address_space(3))) void*)(lds + qb * 8),
            16, 0, 0);
    }
}

// ---------------- conversion kernels ----------------
__global__ __launch_bounds__(256) void conv_split_kernel(
    const float* __restrict__ X, unsigned short* __restrict__ H,
    unsigned short* __restrict__ L, int n4)
{
    int i = blockIdx.x * 256 + threadIdx.x;
    if (i >= n4) return;
    float4 v = ((const float4*)X)[i];
    ushort4 h, l;
    h.x = f32_to_bf16(v.x); l.x = f32_to_bf16(v.x - bf16_to_f32(h.x));
    h.y = f32_to_bf16(v.y); l.y = f32_to_bf16(v.y - bf16_to_f32(h.y));
    h.z = f32_to_bf16(v.z); l.z = f32_to_bf16(v.z - bf16_to_f32(h.z));
    h.w = f32_to_bf16(v.w); l.w = f32_to_bf16(v.w - bf16_to_f32(h.w));
    ((ushort4*)H)[i] = h;
    ((ushort4*)L)[i] = l;
}

__global__ __launch_bounds__(256) void conv_bf16_kernel(
    const float* __restrict__ X, unsigned short* __restrict__ O, int n4)
{
    int i = blockIdx.x * 256 + threadIdx.x;
    if (i >= n4) return;
    float4 v = ((const float4*)X)[i];
    ushort4 o;
    o.x = f32_to_bf16(v.x); o.y = f32_to_bf16(v.y);
    o.z = f32_to_bf16(v.z); o.w = f32_to_bf16(v.w);
    ((ushort4*)O)[i] = o;
}

// Lw [1000,2048] fp32 -> [1024,2048] bf16, zero-padded rows
__global__ __launch_bounds__(256) void conv_lw_kernel(
    const float* __restrict__ Lw, unsigned short* __restrict__ O)
{
    int i = blockIdx.x * 256 + threadIdx.x;   // element group of 4
    int base = i * 4;
    int row = base >> 11;
    ushort4 o;
    if (row < OUT_F) {
        float4 v = ((const float4*)Lw)[i];
        o.x = f32_to_bf16(v.x); o.y = f32_to_bf16(v.y);
        o.z = f32_to_bf16(v.z); o.w = f32_to_bf16(v.w);
    } else {
        o.x = o.y = o.z = o.w = 0;
    }
    ((ushort4*)O)[i] = o;
}

// W [512,2048] fp32 -> Wt hi/lo [2048,512] bf16 (transposed), 64x64 tiles
__global__ __launch_bounds__(256) void conv_wt_kernel(
    const float* __restrict__ W, unsigned short* __restrict__ TH,
    unsigned short* __restrict__ TL)
{
    __shared__ float tile[64][65];
    const int tid = threadIdx.x;
    const int n0 = blockIdx.x * 64;   // rff dim
    const int k0 = blockIdx.y * 64;   // in dim
    #pragma unroll
    for (int i = 0; i < 16; ++i) {
        int e = i * 256 + tid;
        int r = e >> 6, c = e & 63;        // r: k-local, c: n-local
        tile[r][c] = W[(size_t)(k0 + r) * RFF + n0 + c];
    }
    __syncthreads();
    #pragma unroll
    for (int i = 0; i < 16; ++i) {
        int e = i * 256 + tid;
        int r = e >> 6, c = e & 63;        // r: n-local, c: k-local
        float v = tile[c][r];
        unsigned short h = f32_to_bf16(v);
        unsigned short l = f32_to_bf16(v - bf16_to_f32(h));
        TH[(size_t)(n0 + r) * IN_F + k0 + c] = h;
        TL[(size_t)(n0 + r) * IN_F + k0 + c] = l;
    }
}

// ---------------- Kernel 1: Phi = cos(D@W + b)/32 (split bf16 MFMA, dbuf) ----------------
__global__ __launch_bounds__(256) void phi_mfma_kernel(
    const unsigned short* __restrict__ Dh, const unsigned short* __restrict__ Dl,
    const unsigned short* __restrict__ Wth, const unsigned short* __restrict__ Wtl,
    const float* __restrict__ bias, unsigned short* __restrict__ Phi)
{
    __shared__ unsigned short ldsAh[2][4096], ldsAl[2][4096],
                              ldsBh[2][4096], ldsBl[2][4096];
    const int tid = threadIdx.x;
    const int w = tid >> 6, lane = tid & 63;
    const int wm = w >> 1, wn = w & 1;
    const int r0 = blockIdx.y * 128;
    const int c0 = blockIdx.x * 128;

    f32x4 acc[4][4];
    #pragma unroll
    for (int i = 0; i < 4; ++i)
        #pragma unroll
        for (int j = 0; j < 4; ++j)
            acc[i][j] = (f32x4)(0.0f);

    // prologue: stage K-tile 0 into buffer 0
    stage_tile(Dh,  IN_F, r0, 0, ldsAh[0], w, lane);
    stage_tile(Dl,  IN_F, r0, 0, ldsAl[0], w, lane);
    stage_tile(Wth, IN_F, c0, 0, ldsBh[0], w, lane);
    stage_tile(Wtl, IN_F, c0, 0, ldsBl[0], w, lane);

    int cur = 0;
    for (int k0 = 0; k0 < IN_F; k0 += 32) {
        __syncthreads();   // drains vmcnt: buffer `cur` is ready
        if (k0 + 32 < IN_F) {
            int nxt = cur ^ 1;
            stage_tile(Dh,  IN_F, r0, k0 + 32, ldsAh[nxt], w, lane);
            stage_tile(Dl,  IN_F, r0, k0 + 32, ldsAl[nxt], w, lane);
            stage_tile(Wth, IN_F, c0, k0 + 32, ldsBh[nxt], w, lane);
            stage_tile(Wtl, IN_F, c0, k0 + 32, ldsBl[nxt], w, lane);
        }

        short8 fah[4], fal[4], fbh[4], fbl[4];
        #pragma unroll
        for (int t = 0; t < 4; ++t) {
            fah[t] = *(const short8*)(ldsAh[cur] + ((wm * 4 + t) * 64 + lane) * 8);
            fal[t] = *(const short8*)(ldsAl[cur] + ((wm * 4 + t) * 64 + lane) * 8);
            fbh[t] = *(const short8*)(ldsBh[cur] + ((wn * 4 + t) * 64 + lane) * 8);
            fbl[t] = *(const short8*)(ldsBl[cur] + ((wn * 4 + t) * 64 + lane) * 8);
        }
        #pragma unroll
        for (int mt = 0; mt < 4; ++mt)
            #pragma unroll
            for (int nt = 0; nt < 4; ++nt) {
                acc[mt][nt] = __builtin_amdgcn_mfma_f32_16x16x32_bf16(
                    fah[mt], fbh[nt], acc[mt][nt], 0, 0, 0);
                acc[mt][nt] = __builtin_amdgcn_mfma_f32_16x16x32_bf16(
                    fah[mt], fbl[nt], acc[mt][nt], 0, 0, 0);
                acc[mt][nt] = __builtin_amdgcn_mfma_f32_16x16x32_bf16(
                    fal[mt], fbh[nt], acc[mt][nt], 0, 0, 0);
            }
        cur ^= 1;
    }

    const int quad = lane >> 4, ln = lane & 15;
    #pragma unroll
    for (int mt = 0; mt < 4; ++mt)
        #pragma unroll
        for (int nt = 0; nt < 4; ++nt) {
            int col = c0 + wn * 64 + nt * 16 + ln;
            float bv = bias[col];
            #pragma unroll
            for (int reg = 0; reg < 4; ++reg) {
                int row = r0 + wm * 64 + mt * 16 + quad * 4 + reg;
                float z = acc[mt][nt][reg] + bv;
                float p = __cosf(z) * INV_RFF_SCALAR;
                Phi[(size_t)row * RFF + col] = f32_to_bf16(p);
            }
        }
}

// ---------------- Kernel 2: diag += rowsum((Phi@cov).*Phi) (bf16 MFMA, dbuf) ----------------
__global__ __launch_bounds__(256) void diag_mfma_kernel(
    const unsigned short* __restrict__ Phi, const unsigned short* __restrict__ Cov,
    float* __restrict__ diag)
{
    __shared__ unsigned short ldsA[2][4096], ldsB[2][4096];
    const int tid = threadIdx.x;
    const int w = tid >> 6, lane = tid & 63;
    const int wm = w >> 1, wn = w & 1;
    const int r0 = blockIdx.y * 128;
    const int c0 = blockIdx.x * 128;

    f32x4 acc[4][4];
    #pragma unroll
    for (int i = 0; i < 4; ++i)
        #pragma unroll
        for (int j = 0; j < 4; ++j)
            acc[i][j] = (f32x4)(0.0f);

    stage_tile(Phi, RFF, r0, 0, ldsA[0], w, lane);
    stage_tile(Cov, RFF, c0, 0, ldsB[0], w, lane);

    int cur = 0;
    for (int k0 = 0; k0 < RFF; k0 += 32) {
        __syncthreads();
        if (k0 + 32 < RFF) {
            int nxt = cur ^ 1;
            stage_tile(Phi, RFF, r0, k0 + 32, ldsA[nxt], w, lane);
            stage_tile(Cov, RFF, c0, k0 + 32, ldsB[nxt], w, lane);  // cov symmetric
        }

        short8 fa[4], fb[4];
        #pragma unroll
        for (int t = 0; t < 4; ++t) {
            fa[t] = *(const short8*)(ldsA[cur] + ((wm * 4 + t) * 64 + lane) * 8);
            fb[t] = *(const short8*)(ldsB[cur] + ((wn * 4 + t) * 64 + lane) * 8);
        }
        #pragma unroll
        for (int mt = 0; mt < 4; ++mt)
            #pragma unroll
            for (int nt = 0; nt < 4; ++nt)
                acc[mt][nt] = __builtin_amdgcn_mfma_f32_16x16x32_bf16(
                    fa[mt], fb[nt], acc[mt][nt], 0, 0, 0);
        cur ^= 1;
    }

    // epilogue: multiply by Phi elementwise, reduce over this block's 128 cols
    const int quad = lane >> 4, ln = lane & 15;
    #pragma unroll
    for (int mt = 0; mt < 4; ++mt) {
        float psum[4] = {0.f, 0.f, 0.f, 0.f};
        #pragma unroll
        for (int nt = 0; nt < 4; ++nt) {
            int col = c0 + wn * 64 + nt * 16 + ln;
            #pragma unroll
            for (int reg = 0; reg < 4; ++reg) {
                int row = r0 + wm * 64 + mt * 16 + quad * 4 + reg;
                float pv = bf16_to_f32(Phi[(size_t)row * RFF + col]);
                psum[reg] = fmaf(acc[mt][nt][reg], pv, psum[reg]);
            }
        }
        #pragma unroll
        for (int off = 1; off < 16; off <<= 1)
            #pragma unroll
            for (int reg = 0; reg < 4; ++reg)
                psum[reg] += __shfl_xor(psum[reg], off, 16);
        if (ln == 0) {
            #pragma unroll
            for (int reg = 0; reg < 4; ++reg) {
                int row = r0 + wm * 64 + mt * 16 + quad * 4 + reg;
                atomicAdd(&diag[row], psum[reg]);
            }
        }
    }
}

// ---------------- Kernel 3: out = (Phi@LwT + Lb) / sqrt(1+25*diag) (dbuf) ----------------
__global__ __launch_bounds__(256) void pred_mfma_kernel(
    const unsigned short* __restrict__ Phi, const unsigned short* __restrict__ Lw,
    const float* __restrict__ Lb, const float* __restrict__ diag,
    float* __restrict__ out)
{
    __shared__ unsigned short ldsA[2][4096], ldsB[2][4096];
    const int tid = threadIdx.x;
    const int w = tid >> 6, lane = tid & 63;
    const int wm = w >> 1, wn = w & 1;
    const int r0 = blockIdx.y * 128;
    const int c0 = blockIdx.x * 128;

    f32x4 acc[4][4];
    #pragma unroll
    for (int i = 0; i < 4; ++i)
        #pragma unroll
        for (int j = 0; j < 4; ++j)
            acc[i][j] = (f32x4)(0.0f);

    stage_tile(Phi, RFF, r0, 0, ldsA[0], w, lane);
    stage_tile(Lw,  RFF, c0, 0, ldsB[0], w, lane);

    int cur = 0;
    for (int k0 = 0; k0 < RFF; k0 += 32) {
        __syncthreads();
        if (k0 + 32 < RFF) {
            int nxt = cur ^ 1;
            stage_tile(Phi, RFF, r0, k0 + 32, ldsA[nxt], w, lane);
            stage_tile(Lw,  RFF, c0, k0 + 32, ldsB[nxt], w, lane);  // Lw is B^T layout
        }

        short8 fa[4], fb[4];
        #pragma unroll
        for (int t = 0; t < 4; ++t) {
            fa[t] = *(const short8*)(ldsA[cur] + ((wm * 4 + t) * 64 + lane) * 8);
            fb[t] = *(const short8*)(ldsB[cur] + ((wn * 4 + t) * 64 + lane) * 8);
        }
        #pragma unroll
        for (int mt = 0; mt < 4; ++mt)
            #pragma unroll
            for (int nt = 0; nt < 4; ++nt)
                acc[mt][nt] = __builtin_amdgcn_mfma_f32_16x16x32_bf16(
                    fa[mt], fb[nt], acc[mt][nt], 0, 0, 0);
        cur ^= 1;
    }

    const int quad = lane >> 4, ln = lane & 15;
    #pragma unroll
    for (int mt = 0; mt < 4; ++mt) {
        float s[4];
        #pragma unroll
        for (int reg = 0; reg < 4; ++reg) {
            int row = r0 + wm * 64 + mt * 16 + quad * 4 + reg;
            s[reg] = 1.0f / sqrtf(1.0f + MEAN_FIELD * diag[row]);
        }
        #pragma unroll
        for (int nt = 0; nt < 4; ++nt) {
            int col = c0 + wn * 64 + nt * 16 + ln;
            if (col < OUT_F) {
                float bv = Lb[col];
                #pragma unroll
                for (int reg = 0; reg < 4; ++reg) {
                    int row = r0 + wm * 64 + mt * 16 + quad * 4 + reg;
                    out[(size_t)row * OUT_F + col] = (acc[mt][nt][reg] + bv) * s[reg];
                }
            }
        }
    }
}

extern "C" void kernel_launch(void* const* d_in, const int* in_sizes, int n_in,
                              void* d_out, int out_size, void* d_ws, size_t ws_size,
                              hipStream_t stream) {
    const float* D    = (const float*)d_in[0];
    const float* W    = (const float*)d_in[1];
    const float* bias = (const float*)d_in[2];
    const float* Lw   = (const float*)d_in[3];
    const float* Lb   = (const float*)d_in[4];
    const float* cov  = (const float*)d_in[5];
    float* out = (float*)d_out;

    // workspace layout (bytes): total = 67,141,632
    char* p = (char*)d_ws;
    unsigned short* Phi16 = (unsigned short*)p;                 p += (size_t)N_ROWS * RFF * 2;      // 32 MiB
    unsigned short* Dh    = (unsigned short*)p;                 p += (size_t)N_ROWS * IN_F * 2;     // 8 MiB
    unsigned short* Dl    = (unsigned short*)p;                 p += (size_t)N_ROWS * IN_F * 2;     // 8 MiB
    unsigned short* Wth   = (unsigned short*)p;                 p += (size_t)RFF * IN_F * 2;        // 2 MiB
    unsigned short* Wtl   = (unsigned short*)p;                 p += (size_t)RFF * IN_F * 2;        // 2 MiB
    unsigned short* Lw16  = (unsigned short*)p;                 p += (size_t)OUT_PAD * RFF * 2;     // 4 MiB
    unsigned short* Cov16 = (unsigned short*)p;                 p += (size_t)RFF * RFF * 2;         // 8 MiB
    float* diag           = (float*)p;                                                             // 32 KiB

    hipMemsetAsync(diag, 0, N_ROWS * sizeof(float), stream);

    dim3 blk(256);
    conv_split_kernel<<<dim3((N_ROWS * IN_F / 4 + 255) / 256), blk, 0, stream>>>(D, Dh, Dl, N_ROWS * IN_F / 4);
    conv_wt_kernel<<<dim3(RFF / 64, IN_F / 64), blk, 0, stream>>>(W, Wth, Wtl);
    conv_lw_kernel<<<dim3(OUT_PAD * RFF / 4 / 256), blk, 0, stream>>>(Lw, Lw16);
    conv_bf16_kernel<<<dim3(RFF * RFF / 4 / 256), blk, 0, stream>>>(cov, Cov16, RFF * RFF / 4);

    phi_mfma_kernel<<<dim3(RFF / 128, N_ROWS / 128), blk, 0, stream>>>(Dh, Dl, Wth, Wtl, bias, Phi16);
    diag_mfma_kernel<<<dim3(RFF / 128, N_ROWS / 128), blk, 0, stream>>>(Phi16, Cov16, diag);
    pred_mfma_kernel<<<dim3(OUT_PAD / 128, N_ROWS / 128), blk, 0, stream>>>(Phi16, Lw16, Lb, diag, out);
}

// Round 5
// 322.282 us; speedup vs baseline: 1.3523x; 1.3523x over previous
//
#include <hip/hip_runtime.h>
#include <math.h>

#define N_ROWS 8192
#define IN_F   512
#define RFF    2048
#define OUT_F  1000
#define OUT_PAD 1024
#define INV_RFF_SCALAR 0.03125f
#define MEAN_FIELD 25.0f

typedef __attribute__((ext_vector_type(8))) short short8;
typedef __attribute__((ext_vector_type(4))) float f32x4;

// ---------- bf16 helpers (RTN-even) ----------
__device__ __forceinline__ unsigned short f32_to_bf16(float f) {
    unsigned u = __float_as_uint(f);
    unsigned r = 0x7FFFu + ((u >> 16) & 1u);
    return (unsigned short)((u + r) >> 16);
}
__device__ __forceinline__ float bf16_to_f32(unsigned short h) {
    return __uint_as_float(((unsigned)h) << 16);
}

// fragment-chunk global source address for operand X (bf16, row-major, ld=ldx)
// chunk q (0..511): rt=q>>6 (16-row group), L=q&63 (lane): row r0+rt*16+(L&15),
// k = k0 + (L>>4)*8, 8 bf16 = 16B
__device__ __forceinline__ const uint4* gsrc(const unsigned short* X, int ldx,
                                             int r0, int k0, int q) {
    int rt = q >> 6, L = q & 63;
    int r = r0 + rt * 16 + (L & 15);
    int k = k0 + ((L >> 4) << 3);
    return (const uint4*)(X + (size_t)r * ldx + k);
}

// async global->LDS staging of one 128x32 bf16 tile (512 x 16B chunks).
__device__ __forceinline__ void stage_tile(const unsigned short* __restrict__ X, int ldx,
                                           int r0, int k0, unsigned short* lds,
                                           int w, int lane) {
    #pragma unroll
    for (int half = 0; half < 2; ++half) {
        int qb = half * 256 + w * 64;
        const uint4* g = gsrc(X, ldx, r0, k0, qb + lane);
        __builtin_amdgcn_global_load_lds(
            (const __attribute__((address_space(1))) void*)g,
            (__attribute__((address_space(3))) void*)(lds + qb * 8),
            16, 0, 0);
    }
}

// ---------------- conversion kernels ----------------
__global__ __launch_bounds__(256) void conv_split_kernel(
    const float* __restrict__ X, unsigned short* __restrict__ H,
    unsigned short* __restrict__ L, int n4)
{
    int i = blockIdx.x * 256 + threadIdx.x;
    if (i >= n4) return;
    float4 v = ((const float4*)X)[i];
    ushort4 h, l;
    h.x = f32_to_bf16(v.x); l.x = f32_to_bf16(v.x - bf16_to_f32(h.x));
    h.y = f32_to_bf16(v.y); l.y = f32_to_bf16(v.y - bf16_to_f32(h.y));
    h.z = f32_to_bf16(v.z); l.z = f32_to_bf16(v.z - bf16_to_f32(h.z));
    h.w = f32_to_bf16(v.w); l.w = f32_to_bf16(v.w - bf16_to_f32(h.w));
    ((ushort4*)H)[i] = h;
    ((ushort4*)L)[i] = l;
}

// cov [2048,2048] fp32 -> block-triangular-weighted bf16 in B^T layout:
// CovU[n][k] = w * cov[n][k], w = 1 if kblk<nblk, 0.5 if ==, 0 if > (blk=128)
// Then phi^T C phi = 2 * rowsum((Phi @ CovU^T-as-B) .* Phi), K-loop for
// column-block J only needs k < (J+1)*128.
__global__ __launch_bounds__(256) void conv_covu_kernel(
    const float* __restrict__ X, unsigned short* __restrict__ O)
{
    int i = blockIdx.x * 256 + threadIdx.x;   // float4 group
    int base = i * 4;
    int row = base >> 11;          // n
    int col = base & 2047;         // k (all 4 in same 128-block)
    int bn = row >> 7, bk = col >> 7;
    float w = (bk < bn) ? 1.0f : (bk == bn ? 0.5f : 0.0f);
    float4 v = ((const float4*)X)[i];
    ushort4 o;
    o.x = f32_to_bf16(v.x * w); o.y = f32_to_bf16(v.y * w);
    o.z = f32_to_bf16(v.z * w); o.w = f32_to_bf16(v.w * w);
    ((ushort4*)O)[i] = o;
}

// Lw [1000,2048] fp32 -> [1024,2048] bf16, zero-padded rows
__global__ __launch_bounds__(256) void conv_lw_kernel(
    const float* __restrict__ Lw, unsigned short* __restrict__ O)
{
    int i = blockIdx.x * 256 + threadIdx.x;   // element group of 4
    int base = i * 4;
    int row = base >> 11;
    ushort4 o;
    if (row < OUT_F) {
        float4 v = ((const float4*)Lw)[i];
        o.x = f32_to_bf16(v.x); o.y = f32_to_bf16(v.y);
        o.z = f32_to_bf16(v.z); o.w = f32_to_bf16(v.w);
    } else {
        o.x = o.y = o.z = o.w = 0;
    }
    ((ushort4*)O)[i] = o;
}

// W [512,2048] fp32 -> Wt hi/lo [2048,512] bf16 (transposed), 64x64 tiles
__global__ __launch_bounds__(256) void conv_wt_kernel(
    const float* __restrict__ W, unsigned short* __restrict__ TH,
    unsigned short* __restrict__ TL)
{
    __shared__ float tile[64][65];
    const int tid = threadIdx.x;
    const int n0 = blockIdx.x * 64;   // rff dim
    const int k0 = blockIdx.y * 64;   // in dim
    #pragma unroll
    for (int i = 0; i < 16; ++i) {
        int e = i * 256 + tid;
        int r = e >> 6, c = e & 63;        // r: k-local, c: n-local
        tile[r][c] = W[(size_t)(k0 + r) * RFF + n0 + c];
    }
    __syncthreads();
    #pragma unroll
    for (int i = 0; i < 16; ++i) {
        int e = i * 256 + tid;
        int r = e >> 6, c = e & 63;        // r: n-local, c: k-local
        float v = tile[c][r];
        unsigned short h = f32_to_bf16(v);
        unsigned short l = f32_to_bf16(v - bf16_to_f32(h));
        TH[(size_t)(n0 + r) * IN_F + k0 + c] = h;
        TL[(size_t)(n0 + r) * IN_F + k0 + c] = l;
    }
}

// ---------------- Kernel 1: Phi = cos(D@W + b)/32 (split bf16 MFMA) ----------------
__global__ __launch_bounds__(256) void phi_mfma_kernel(
    const unsigned short* __restrict__ Dh, const unsigned short* __restrict__ Dl,
    const unsigned short* __restrict__ Wth, const unsigned short* __restrict__ Wtl,
    const float* __restrict__ bias, unsigned short* __restrict__ Phi)
{
    __shared__ unsigned short ldsAh[4096], ldsAl[4096], ldsBh[4096], ldsBl[4096];
    const int tid = threadIdx.x;
    const int w = tid >> 6, lane = tid & 63;
    const int wm = w >> 1, wn = w & 1;
    const int r0 = blockIdx.y * 128;
    const int c0 = blockIdx.x * 128;

    f32x4 acc[4][4];
    #pragma unroll
    for (int i = 0; i < 4; ++i)
        #pragma unroll
        for (int j = 0; j < 4; ++j)
            acc[i][j] = (f32x4)(0.0f);

    for (int k0 = 0; k0 < IN_F; k0 += 32) {
        __syncthreads();   // previous iteration's ds_reads complete
        stage_tile(Dh,  IN_F, r0, k0, ldsAh, w, lane);
        stage_tile(Dl,  IN_F, r0, k0, ldsAl, w, lane);
        stage_tile(Wth, IN_F, c0, k0, ldsBh, w, lane);
        stage_tile(Wtl, IN_F, c0, k0, ldsBl, w, lane);
        __syncthreads();   // vmcnt drain + barrier

        short8 fah[4], fal[4], fbh[4], fbl[4];
        #pragma unroll
        for (int t = 0; t < 4; ++t) {
            fah[t] = *(const short8*)(ldsAh + ((wm * 4 + t) * 64 + lane) * 8);
            fal[t] = *(const short8*)(ldsAl + ((wm * 4 + t) * 64 + lane) * 8);
            fbh[t] = *(const short8*)(ldsBh + ((wn * 4 + t) * 64 + lane) * 8);
            fbl[t] = *(const short8*)(ldsBl + ((wn * 4 + t) * 64 + lane) * 8);
        }
        #pragma unroll
        for (int mt = 0; mt < 4; ++mt)
            #pragma unroll
            for (int nt = 0; nt < 4; ++nt) {
                acc[mt][nt] = __builtin_amdgcn_mfma_f32_16x16x32_bf16(
                    fah[mt], fbh[nt], acc[mt][nt], 0, 0, 0);
                acc[mt][nt] = __builtin_amdgcn_mfma_f32_16x16x32_bf16(
                    fah[mt], fbl[nt], acc[mt][nt], 0, 0, 0);
                acc[mt][nt] = __builtin_amdgcn_mfma_f32_16x16x32_bf16(
                    fal[mt], fbh[nt], acc[mt][nt], 0, 0, 0);
            }
    }

    const int quad = lane >> 4, ln = lane & 15;
    #pragma unroll
    for (int mt = 0; mt < 4; ++mt)
        #pragma unroll
        for (int nt = 0; nt < 4; ++nt) {
            int col = c0 + wn * 64 + nt * 16 + ln;
            float bv = bias[col];
            #pragma unroll
            for (int reg = 0; reg < 4; ++reg) {
                int row = r0 + wm * 64 + mt * 16 + quad * 4 + reg;
                float z = acc[mt][nt][reg] + bv;
                float p = __cosf(z) * INV_RFF_SCALAR;
                Phi[(size_t)row * RFF + col] = f32_to_bf16(p);
            }
        }
}

// ------- Kernel 2: diag = 2*rowsum((Phi@CovU_B).*Phi), triangular K -------
__global__ __launch_bounds__(256) void diag_mfma_kernel(
    const unsigned short* __restrict__ Phi, const unsigned short* __restrict__ CovU,
    float* __restrict__ diag)
{
    __shared__ unsigned short ldsA[4096], ldsB[4096];
    const int tid = threadIdx.x;
    const int w = tid >> 6, lane = tid & 63;
    const int wm = w >> 1, wn = w & 1;
    const int J = (RFF / 128 - 1) - blockIdx.y;  // reversed: longest K first
    const int r0 = blockIdx.x * 128;
    const int c0 = J * 128;
    const int kmax = (J + 1) * 128;

    f32x4 acc[4][4];
    #pragma unroll
    for (int i = 0; i < 4; ++i)
        #pragma unroll
        for (int j = 0; j < 4; ++j)
            acc[i][j] = (f32x4)(0.0f);

    for (int k0 = 0; k0 < kmax; k0 += 32) {
        __syncthreads();
        stage_tile(Phi,  RFF, r0, k0, ldsA, w, lane);
        stage_tile(CovU, RFF, c0, k0, ldsB, w, lane);  // pre-weighted B^T layout
        __syncthreads();

        short8 fa[4], fb[4];
        #pragma unroll
        for (int t = 0; t < 4; ++t) {
            fa[t] = *(const short8*)(ldsA + ((wm * 4 + t) * 64 + lane) * 8);
            fb[t] = *(const short8*)(ldsB + ((wn * 4 + t) * 64 + lane) * 8);
        }
        #pragma unroll
        for (int mt = 0; mt < 4; ++mt)
            #pragma unroll
            for (int nt = 0; nt < 4; ++nt)
                acc[mt][nt] = __builtin_amdgcn_mfma_f32_16x16x32_bf16(
                    fa[mt], fb[nt], acc[mt][nt], 0, 0, 0);
    }

    // epilogue: multiply by Phi elementwise, reduce, x2 (triangle fold)
    const int quad = lane >> 4, ln = lane & 15;
    #pragma unroll
    for (int mt = 0; mt < 4; ++mt) {
        float psum[4] = {0.f, 0.f, 0.f, 0.f};
        #pragma unroll
        for (int nt = 0; nt < 4; ++nt) {
            int col = c0 + wn * 64 + nt * 16 + ln;
            #pragma unroll
            for (int reg = 0; reg < 4; ++reg) {
                int row = r0 + wm * 64 + mt * 16 + quad * 4 + reg;
                float pv = bf16_to_f32(Phi[(size_t)row * RFF + col]);
                psum[reg] = fmaf(acc[mt][nt][reg], pv, psum[reg]);
            }
        }
        #pragma unroll
        for (int off = 1; off < 16; off <<= 1)
            #pragma unroll
            for (int reg = 0; reg < 4; ++reg)
                psum[reg] += __shfl_xor(psum[reg], off, 16);
        if (ln == 0) {
            #pragma unroll
            for (int reg = 0; reg < 4; ++reg) {
                int row = r0 + wm * 64 + mt * 16 + quad * 4 + reg;
                atomicAdd(&diag[row], 2.0f * psum[reg]);
            }
        }
    }
}

// ---------------- Kernel 3: out = (Phi@LwT + Lb) / sqrt(1+25*diag) ----------------
__global__ __launch_bounds__(256) void pred_mfma_kernel(
    const unsigned short* __restrict__ Phi, const unsigned short* __restrict__ Lw,
    const float* __restrict__ Lb, const float* __restrict__ diag,
    float* __restrict__ out)
{
    __shared__ unsigned short ldsA[4096], ldsB[4096];
    const int tid = threadIdx.x;
    const int w = tid >> 6, lane = tid & 63;
    const int wm = w >> 1, wn = w & 1;
    const int r0 = blockIdx.y * 128;
    const int c0 = blockIdx.x * 128;

    f32x4 acc[4][4];
    #pragma unroll
    for (int i = 0; i < 4; ++i)
        #pragma unroll
        for (int j = 0; j < 4; ++j)
            acc[i][j] = (f32x4)(0.0f);

    for (int k0 = 0; k0 < RFF; k0 += 32) {
        __syncthreads();
        stage_tile(Phi, RFF, r0, k0, ldsA, w, lane);
        stage_tile(Lw,  RFF, c0, k0, ldsB, w, lane);   // Lw is [out,rff] = B^T layout
        __syncthreads();

        short8 fa[4], fb[4];
        #pragma unroll
        for (int t = 0; t < 4; ++t) {
            fa[t] = *(const short8*)(ldsA + ((wm * 4 + t) * 64 + lane) * 8);
            fb[t] = *(const short8*)(ldsB + ((wn * 4 + t) * 64 + lane) * 8);
        }
        #pragma unroll
        for (int mt = 0; mt < 4; ++mt)
            #pragma unroll
            for (int nt = 0; nt < 4; ++nt)
                acc[mt][nt] = __builtin_amdgcn_mfma_f32_16x16x32_bf16(
                    fa[mt], fb[nt], acc[mt][nt], 0, 0, 0);
    }

    const int quad = lane >> 4, ln = lane & 15;
    #pragma unroll
    for (int mt = 0; mt < 4; ++mt) {
        float s[4];
        #pragma unroll
        for (int reg = 0; reg < 4; ++reg) {
            int row = r0 + wm * 64 + mt * 16 + quad * 4 + reg;
            s[reg] = 1.0f / sqrtf(1.0f + MEAN_FIELD * diag[row]);
        }
        #pragma unroll
        for (int nt = 0; nt < 4; ++nt) {
            int col = c0 + wn * 64 + nt * 16 + ln;
            if (col < OUT_F) {
                float bv = Lb[col];
                #pragma unroll
                for (int reg = 0; reg < 4; ++reg) {
                    int row = r0 + wm * 64 + mt * 16 + quad * 4 + reg;
                    out[(size_t)row * OUT_F + col] = (acc[mt][nt][reg] + bv) * s[reg];
                }
            }
        }
    }
}

extern "C" void kernel_launch(void* const* d_in, const int* in_sizes, int n_in,
                              void* d_out, int out_size, void* d_ws, size_t ws_size,
                              hipStream_t stream) {
    const float* D    = (const float*)d_in[0];
    const float* W    = (const float*)d_in[1];
    const float* bias = (const float*)d_in[2];
    const float* Lw   = (const float*)d_in[3];
    const float* Lb   = (const float*)d_in[4];
    const float* cov  = (const float*)d_in[5];
    float* out = (float*)d_out;

    // workspace layout (bytes): total = 67,141,632
    char* p = (char*)d_ws;
    unsigned short* Phi16 = (unsigned short*)p;                 p += (size_t)N_ROWS * RFF * 2;      // 32 MiB
    unsigned short* Dh    = (unsigned short*)p;                 p += (size_t)N_ROWS * IN_F * 2;     // 8 MiB
    unsigned short* Dl    = (unsigned short*)p;                 p += (size_t)N_ROWS * IN_F * 2;     // 8 MiB
    unsigned short* Wth   = (unsigned short*)p;                 p += (size_t)RFF * IN_F * 2;        // 2 MiB
    unsigned short* Wtl   = (unsigned short*)p;                 p += (size_t)RFF * IN_F * 2;        // 2 MiB
    unsigned short* Lw16  = (unsigned short*)p;                 p += (size_t)OUT_PAD * RFF * 2;     // 4 MiB
    unsigned short* CovU  = (unsigned short*)p;                 p += (size_t)RFF * RFF * 2;         // 8 MiB
    float* diag           = (float*)p;                                                             // 32 KiB

    hipMemsetAsync(diag, 0, N_ROWS * sizeof(float), stream);

    dim3 blk(256);
    conv_split_kernel<<<dim3((N_ROWS * IN_F / 4 + 255) / 256), blk, 0, stream>>>(D, Dh, Dl, N_ROWS * IN_F / 4);
    conv_wt_kernel<<<dim3(RFF / 64, IN_F / 64), blk, 0, stream>>>(W, Wth, Wtl);
    conv_lw_kernel<<<dim3(OUT_PAD * RFF / 4 / 256), blk, 0, stream>>>(Lw, Lw16);
    conv_covu_kernel<<<dim3(RFF * RFF / 4 / 256), blk, 0, stream>>>(cov, CovU);

    phi_mfma_kernel<<<dim3(RFF / 128, N_ROWS / 128), blk, 0, stream>>>(Dh, Dl, Wth, Wtl, bias, Phi16);
    diag_mfma_kernel<<<dim3(N_ROWS / 128, RFF / 128), blk, 0, stream>>>(Phi16, CovU, diag);
    pred_mfma_kernel<<<dim3(OUT_PAD / 128, N_ROWS / 128), blk, 0, stream>>>(Phi16, Lw16, Lb, diag, out);
}